// Round 8
// baseline (283.928 us; speedup 1.0000x reference)
//
#include <hip/hip_runtime.h>
#include <math.h>

#define N_NODES 150000
#define N_EDGES 1200000
#define C 64
#define ACT 6
#define B_ROWS 25000   // N/ACT
#define GLOB 256
#define GOUT 10
#define H 32

#define NPAD 150016            // N rounded up (alignment)

// ---- edge sort geometry ----
#define CHUNK_E 4096           // edges per chunk (512 thr * 8)
#define NCHUNK 293             // ceil(1.2M/4096)
#define NBIN 1172              // ceil(150000/128): coarse bin = dst>>7
#define S4CAP 2048             // per-bin capacity (mean 1024, sigma 32 -> 32 sigma)

// k1' = hist || cast || prep (512 threads)
#define HIST_BLOCKS 293
#define CAST_BLOCKS 2344       // 9.6M elems / (512*8)
#define PREP_BLOCKS 216        // 110592/512

// k2' = gemm1 || conv (512 threads)
#define GEMM1_BLOCKS 784       // 196 mb * 4 col-quarters
#define CONV_BLOCKS2 1172      // ceil(9375 row-tiles / 8 waves)

// k3 = fused gather+gemm2+mlp: 96 nodes/block, 384 threads
#define FUSED_BLOCKS 1563      // ceil(150000/96)

typedef short bf16x8 __attribute__((ext_vector_type(8)));
typedef float f32x4v __attribute__((ext_vector_type(4)));

// ---- bf16 helpers ----
__device__ __forceinline__ unsigned short f2bf(float f) {
    unsigned int u = __builtin_bit_cast(unsigned int, f);
    unsigned int r = (u + 0x7fffu + ((u >> 16) & 1u)) >> 16;   // RTNE
    return (unsigned short)r;
}
__device__ __forceinline__ unsigned int pack2bf(float a, float b) {
    return (unsigned int)f2bf(a) | ((unsigned int)f2bf(b) << 16);
}
__device__ __forceinline__ float bflo(unsigned int u) {
    return __builtin_bit_cast(float, u << 16);
}
__device__ __forceinline__ float bfhi(unsigned int u) {
    return __builtin_bit_cast(float, u & 0xffff0000u);
}

// ======== k1': coarse histogram (LDS atomics only) || state->bf16 cast || weight prep ========
__global__ __launch_bounds__(512) void k1_hist_cast_prep(
        const int* __restrict__ dst, int* __restrict__ hist,   // [NBIN][NCHUNK]
        const float* __restrict__ state, unsigned short* __restrict__ sb,
        const float* __restrict__ convW, const float* __restrict__ gW1,
        const float* __restrict__ gW2,
        const float* __restrict__ l1W, const float* __restrict__ l2W,
        unsigned short* __restrict__ wcb, unsigned short* __restrict__ w1b,
        unsigned short* __restrict__ w1p, unsigned short* __restrict__ w2p,
        unsigned short* __restrict__ w2b, int E) {
    int bi = blockIdx.x;
    int t  = threadIdx.x;
    if (bi < HIST_BLOCKS) {
        __shared__ int h[NBIN];
        for (int i = t; i < NBIN; i += 512) h[i] = 0;
        __syncthreads();
        int e0 = bi * CHUNK_E + t * 8;
        if (e0 + 8 <= E) {
            int4 a = *(const int4*)(dst + e0);
            int4 b = *(const int4*)(dst + e0 + 4);
            atomicAdd(&h[a.x >> 7], 1); atomicAdd(&h[a.y >> 7], 1);
            atomicAdd(&h[a.z >> 7], 1); atomicAdd(&h[a.w >> 7], 1);
            atomicAdd(&h[b.x >> 7], 1); atomicAdd(&h[b.y >> 7], 1);
            atomicAdd(&h[b.z >> 7], 1); atomicAdd(&h[b.w >> 7], 1);
        } else {
            for (int e = e0; e < E; ++e) atomicAdd(&h[dst[e] >> 7], 1);
        }
        __syncthreads();
        for (int i = t; i < NBIN; i += 512) hist[(size_t)i * NCHUNK + bi] = h[i];
        return;
    }
    bi -= HIST_BLOCKS;
    if (bi < CAST_BLOCKS) {
        int idx = (bi * 512 + t) * 8;
        if (idx < N_NODES * C) {
            float4 a = *(const float4*)(state + idx);
            float4 b = *(const float4*)(state + idx + 4);
            uint4 o = make_uint4(pack2bf(a.x, a.y), pack2bf(a.z, a.w),
                                 pack2bf(b.x, b.y), pack2bf(b.z, b.w));
            *(uint4*)(sb + idx) = o;
        }
        return;
    }
    bi -= CAST_BLOCKS;
    int j = bi * 512 + t;
    if (j < 4096) {
        wcb[j] = f2bf(convW[j]);
    } else if (j < 102400) {
        int k = j - 4096;
        w1b[k] = f2bf(gW1[k]);
    } else if (j < 105472) {
        int k = j - 102400;
        int r = k / 96, c = k - r * 96;
        w1p[k] = (c < 74) ? f2bf(l1W[r * 74 + c]) : 0;
    } else if (j < 106496) {
        int k = j - 105472;
        w2p[k] = f2bf(l2W[k]);
    } else {
        int k = j - 106496;          // j < 110592 exactly (216 blocks of 512)
        int r = k >> 8, c = k & 255;
        w2b[k] = (r < 10) ? f2bf(gW2[r * 256 + c]) : 0;
    }
}

// ======== sort_scan: per-bin chunk prefix + decoupled-lookback bin prefix ========
// hist in: counts [NBIN][NCHUNK]; out: absolute base per (bin,chunk). binStart[NBIN+1].
__global__ __launch_bounds__(512) void sort_scan(
        int* __restrict__ hist, int* __restrict__ binStart,
        unsigned int* __restrict__ flags, unsigned int* __restrict__ ticket,
        float* __restrict__ regptr) {
    __shared__ int lds[512];
    __shared__ int bidS;
    __shared__ int startS;
    int t = threadIdx.x;
    if (t == 0) bidS = (int)atomicAdd(ticket, 1u);
    __syncthreads();
    int b = bidS;

    int v = (t < NCHUNK) ? hist[(size_t)b * NCHUNK + t] : 0;
    lds[t] = v; __syncthreads();
    for (int off = 1; off < 512; off <<= 1) {
        int x = (t >= off) ? lds[t - off] : 0;
        __syncthreads();
        lds[t] += x;
        __syncthreads();
    }
    int excl  = lds[t] - v;
    int total = lds[511];

    if (t == 0) {
        if (b == 0) {
            atomicExch(&flags[0], (2u << 30) | (unsigned)total);
            startS = 0;
            *regptr = 0.f;
        } else {
            atomicExch(&flags[b], (1u << 30) | (unsigned)total);
            int sum = 0;
            int j = b - 1;
            while (true) {
                unsigned f;
                do { f = atomicAdd(&flags[j], 0u); } while ((f >> 30) == 0u);
                sum += (int)(f & 0x3fffffffu);
                if ((f >> 30) == 2u) break;
                --j;
            }
            startS = sum;
            atomicExch(&flags[b], (2u << 30) | (unsigned)(sum + total));
        }
        binStart[b] = startS;
        if (b == NBIN - 1) binStart[NBIN] = startS + total;
    }
    __syncthreads();
    if (t < NCHUNK) hist[(size_t)b * NCHUNK + t] = startS + excl;
}

// ======== sort_scatter: bucket (src,dst) pairs by coarse bin ========
__global__ __launch_bounds__(512) void sort_scatter(
        const int* __restrict__ src, const int* __restrict__ dst,
        const int* __restrict__ absBase, int2* __restrict__ bb, int E) {
    __shared__ int cnt[NBIN];
    int bi = blockIdx.x;
    int t  = threadIdx.x;
    for (int i = t; i < NBIN; i += 512) cnt[i] = 0;
    __syncthreads();
    int e0 = bi * CHUNK_E + t * 8;
    #pragma unroll
    for (int k = 0; k < 8; ++k) {
        int e = e0 + k;
        if (e < E) {
            int d = dst[e];
            int s = src[e];
            int bin = d >> 7;
            int r = atomicAdd(&cnt[bin], 1);
            int pos = absBase[(size_t)bin * NCHUNK + bi] + r;
            bb[pos] = make_int2(s, d);
        }
    }
}

// ======== sort_finalize: per-bin 128-way LDS sort -> csr + rowptr + dinv ========
__global__ __launch_bounds__(512) void sort_finalize(
        const int2* __restrict__ bb, const int* __restrict__ binStart,
        int* __restrict__ csr, int* __restrict__ rowptr, float* __restrict__ dinv,
        int n) {
    __shared__ int2 pairs[S4CAP];
    __shared__ int srcS[S4CAP];
    __shared__ int hist[128];
    __shared__ int offs[128];
    __shared__ int cur[128];
    int b = blockIdx.x;
    int t = threadIdx.x;
    int beg = binStart[b], end = binStart[b + 1];
    int cnt = end - beg;
    if (cnt > S4CAP) cnt = S4CAP;                 // 32-sigma guard
    if (t < 128) hist[t] = 0;
    __syncthreads();
    for (int i = t; i < cnt; i += 512) {
        int2 p = bb[beg + i];
        pairs[i] = p;
        atomicAdd(&hist[p.y & 127], 1);
    }
    __syncthreads();
    if (t < 128) offs[t] = hist[t];
    __syncthreads();
    for (int off = 1; off < 128; off <<= 1) {
        int x = 0;
        if (t < 128 && t >= off) x = offs[t - off];
        __syncthreads();
        if (t < 128) offs[t] += x;                // inclusive
        __syncthreads();
    }
    if (t < 128) cur[t] = offs[t] - hist[t];      // exclusive
    __syncthreads();
    for (int i = t; i < cnt; i += 512) {
        int2 p = pairs[i];
        int r = atomicAdd(&cur[p.y & 127], 1);
        srcS[r] = p.x;
    }
    __syncthreads();
    for (int i = t; i < cnt; i += 512) csr[beg + i] = srcS[i];
    if (t < 128) {
        int node = b * 128 + t;
        if (node <= n) {
            rowptr[node] = beg + (offs[t] - hist[t]);
            if (node < n) dinv[node] = rsqrtf((float)hist[t] + 1.0f);
        }
    }
}

// ======== k2': gemm1 (MFMA, K-split 25.6KB LDS, bf16 A) || conv (MFMA, bf16 A) ========
#define BS2 200   // shorts per LDS row: 192 cols + 8 pad
__global__ __launch_bounds__(512, 8) void k2_gemm1_conv(
        const unsigned short* __restrict__ sb,    // bf16(state): [150000][64] == [25000][384]
        const unsigned short* __restrict__ wcb,
        const float* __restrict__ dinv,
        unsigned short* __restrict__ hb,
        const unsigned short* __restrict__ Wb,    // w1b [256][384] bf16
        const float* __restrict__ bias,           // gb1
        unsigned short* __restrict__ y1b,         // [25000][256] bf16 out
        int n, int M) {
    __shared__ unsigned short Blds[64 * BS2];     // 25600 B -> 4 blocks/CU (wave cap)

    int bi  = blockIdx.x;
    int tid = threadIdx.x;

    if (bi < GEMM1_BLOCKS) {
        // ---- gemm1: y1 = leaky(sb[25000][384] @ W1^T[384][256] + b1) ----
        int mb   = bi >> 2;
        int q    = bi & 3;
        int col0 = q * 64;

        int wave = tid >> 6;
        int lane = tid & 63;
        int quad = lane >> 4;
        int lm   = lane & 15;
        int row0 = mb * 128 + wave * 16;
        int arow = row0 + lm;
        if (arow >= M) arow = M - 1;
        const unsigned short* ap = sb + (size_t)arow * 384 + quad * 8;

        f32x4v acc[4];
        #pragma unroll
        for (int t = 0; t < 4; ++t) acc[t] = (f32x4v){0.f, 0.f, 0.f, 0.f};

        // ---- stage 0: K cols [0,192) ----
        #pragma unroll
        for (int i = 0; i < 3; ++i) {
            int seg = i * 512 + tid;
            int row = seg / 24;                  // 24 uint4 per row
            int off = (seg - row * 24) * 8;
            *(uint4*)(&Blds[row * BS2 + off]) = *(const uint4*)(Wb + (size_t)(col0 + row) * 384 + off);
        }
        {
            bf16x8 af[6];
            #pragma unroll
            for (int ks = 0; ks < 6; ++ks) af[ks] = *(const bf16x8*)(ap + ks * 32);
            __syncthreads();
            #pragma unroll
            for (int ks = 0; ks < 6; ++ks) {
                #pragma unroll
                for (int t = 0; t < 4; ++t) {
                    bf16x8 bfr = *(const bf16x8*)(&Blds[(t * 16 + lm) * BS2 + ks * 32 + quad * 8]);
                    acc[t] = __builtin_amdgcn_mfma_f32_16x16x32_bf16(af[ks], bfr, acc[t], 0, 0, 0);
                }
            }
        }
        __syncthreads();
        // ---- stage 1: K cols [192,384) ----
        #pragma unroll
        for (int i = 0; i < 3; ++i) {
            int seg = i * 512 + tid;
            int row = seg / 24;
            int off = (seg - row * 24) * 8;
            *(uint4*)(&Blds[row * BS2 + off]) = *(const uint4*)(Wb + (size_t)(col0 + row) * 384 + 192 + off);
        }
        {
            bf16x8 af[6];
            #pragma unroll
            for (int ks = 0; ks < 6; ++ks) af[ks] = *(const bf16x8*)(ap + 192 + ks * 32);
            __syncthreads();
            #pragma unroll
            for (int ks = 0; ks < 6; ++ks) {
                #pragma unroll
                for (int t = 0; t < 4; ++t) {
                    bf16x8 bfr = *(const bf16x8*)(&Blds[(t * 16 + lm) * BS2 + ks * 32 + quad * 8]);
                    acc[t] = __builtin_amdgcn_mfma_f32_16x16x32_bf16(af[ks], bfr, acc[t], 0, 0, 0);
                }
            }
        }

        #pragma unroll
        for (int t = 0; t < 4; ++t) {
            int nn = col0 + t * 16 + lm;
            float bv = bias[nn];
            #pragma unroll
            for (int r = 0; r < 4; ++r) {
                int m = row0 + quad * 4 + r;
                if (m < M) {
                    float v = acc[t][r] + bv;
                    v = (v > 0.f) ? v : 0.01f * v;
                    y1b[(size_t)m * 256 + nn] = f2bf(v);
                }
            }
        }
        return;
    }

    // ---- conv: h = bf16(sb @ convW^T) * dinv ----
    int cb   = bi - GEMM1_BLOCKS;
    int wid  = tid >> 6;
    int lane = tid & 63;
    int quad = lane >> 4;
    int lm   = lane & 15;
    int row0 = (cb * 8 + wid) * 16;
    if (row0 >= n) return;                    // n = 150000 = 16*9375

    const unsigned short* ap = sb + (size_t)(row0 + lm) * 64 + quad * 8;
    bf16x8 a0 = *(const bf16x8*)ap;
    bf16x8 a1 = *(const bf16x8*)(ap + 32);

    f32x4v acc[4];
    #pragma unroll
    for (int t = 0; t < 4; ++t) acc[t] = (f32x4v){0.f, 0.f, 0.f, 0.f};
    #pragma unroll
    for (int t = 0; t < 4; ++t) {
        const unsigned short* bp = wcb + (size_t)(t * 16 + lm) * 64 + quad * 8;
        bf16x8 b0 = *(const bf16x8*)bp;
        bf16x8 b1 = *(const bf16x8*)(bp + 32);
        acc[t] = __builtin_amdgcn_mfma_f32_16x16x32_bf16(a0, b0, acc[t], 0, 0, 0);
        acc[t] = __builtin_amdgcn_mfma_f32_16x16x32_bf16(a1, b1, acc[t], 0, 0, 0);
    }

    float dv[4];
    #pragma unroll
    for (int r = 0; r < 4; ++r) dv[r] = dinv[row0 + quad * 4 + r];
    #pragma unroll
    for (int t = 0; t < 4; ++t) {
        #pragma unroll
        for (int r = 0; r < 4; ++r) {
            int m = row0 + quad * 4 + r;
            hb[(size_t)m * 64 + t * 16 + lm] = f2bf(acc[t][r] * dv[r]);
        }
    }
}

// ======== k3: fused gather (4 lanes/node, 2-deep, LDS x) + inline gemm2 + MLP ========
#define XB_STRIDE 72    // shorts; 144B rows -> 16B-aligned uint4, 2-way-free bank stride
#define Y1_STRIDE 40
__global__ __launch_bounds__(384, 6) void k3_fused(
        const int* __restrict__ rowptr, const int* __restrict__ csr,
        const unsigned short* __restrict__ hb, const unsigned short* __restrict__ sb,
        const float* __restrict__ dinv, const float* __restrict__ convb,
        const unsigned short* __restrict__ y1b,   // [25000][256] bf16
        const unsigned short* __restrict__ w2b,   // [16][256] bf16 zero-padded
        const float* __restrict__ b2,             // gb2 [10]
        const unsigned short* __restrict__ w1p,   // [32][96] bf16 zero-padded
        const unsigned short* __restrict__ w2p,   // [32][32] bf16
        const float* __restrict__ l1b, const float* __restrict__ l2b,
        const float* __restrict__ l3W, const float* __restrict__ l3b,
        float* __restrict__ out, float* __restrict__ regptr,
        int n, int E, int M) {
    __shared__ unsigned short xbL[96 * XB_STRIDE];   // 13824 B: x = relu(conv)+state, bf16
    __shared__ unsigned short xgL[16 * 16];          // 512 B: this block's 16 gemm2 rows
    __shared__ unsigned short y1L[6][16 * Y1_STRIDE];
    __shared__ float conc[96];
    __shared__ float wsum[6];

    int tid  = threadIdx.x;
    int wid  = tid >> 6;
    int lane = tid & 63;
    int nbase = blockIdx.x * 96;
    int brow0 = nbase / 6;                     // 16 B-rows per block

    // ---- inline gemm2 on wave 0: xg[brow0..brow0+16) = leaky(y1 @ W2^T + b2) ----
    if (wid == 0) {
        int quad = lane >> 4;
        int lm   = lane & 15;
        int arow = brow0 + lm;
        if (arow >= M) arow = M - 1;
        const unsigned short* ap = y1b + (size_t)arow * 256 + quad * 8;
        const unsigned short* bp = w2b + (size_t)lm * 256 + quad * 8;
        f32x4v acc2 = (f32x4v){0.f, 0.f, 0.f, 0.f};
        #pragma unroll
        for (int ks = 0; ks < 8; ++ks) {
            bf16x8 a = *(const bf16x8*)(ap + ks * 32);
            bf16x8 b = *(const bf16x8*)(bp + ks * 32);
            acc2 = __builtin_amdgcn_mfma_f32_16x16x32_bf16(a, b, acc2, 0, 0, 0);
        }
        float bv = (lane & 15) < 10 ? b2[lane & 15] : 0.f;
        #pragma unroll
        for (int r = 0; r < 4; ++r) {
            float v = acc2[r] + bv;
            v = (v > 0.f) ? v : 0.01f * v;     // rows >=10: W=0,b=0 -> exact 0
            xgL[(quad * 4 + r) * 16 + lm] = f2bf(v);
        }
    }

    // ---- gather: 6 waves x 16 nodes, 4 lanes/node (16 channels/lane), 2 neighbors/iter ----
    {
        int g   = lane >> 2;
        int sub = lane & 3;
        int node = nbase + wid * 16 + g;
        bool valid = node < n;
        int nodec = valid ? node : (n - 1);
        int beg = rowptr[nodec], end = rowptr[nodec + 1];
        int deg = valid ? (end - beg) : 0;

        float acc[16];
        #pragma unroll
        for (int j = 0; j < 16; ++j) acc[j] = 0.f;

        int eid = 0;
        for (int i = 0; i < deg; i += 2) {
            if ((i & 3) == 0) {
                int q2 = beg + i + sub; if (q2 > E - 1) q2 = E - 1;
                eid = csr[q2];
            }
            int rem = deg - i;                        // >= 1, group-uniform
            int b0  = (g << 2) + (i & 2);
            int s0 = __shfl(eid, b0, 64);
            int s1 = __shfl(eid, b0 + 1, 64);
            const unsigned short* h0 = hb + (size_t)s0 * 64 + sub * 16;
            uint4 x0 = *(const uint4*)h0;
            uint4 x1 = *(const uint4*)(h0 + 8);
            uint4 z0 = make_uint4(0u, 0u, 0u, 0u), z1 = z0;
            if (rem > 1) {
                const unsigned short* h1 = hb + (size_t)s1 * 64 + sub * 16;
                z0 = *(const uint4*)h1;
                z1 = *(const uint4*)(h1 + 8);
            }
            acc[0]  += bflo(x0.x) + bflo(z0.x);  acc[1]  += bfhi(x0.x) + bfhi(z0.x);
            acc[2]  += bflo(x0.y) + bflo(z0.y);  acc[3]  += bfhi(x0.y) + bfhi(z0.y);
            acc[4]  += bflo(x0.z) + bflo(z0.z);  acc[5]  += bfhi(x0.z) + bfhi(z0.z);
            acc[6]  += bflo(x0.w) + bflo(z0.w);  acc[7]  += bfhi(x0.w) + bfhi(z0.w);
            acc[8]  += bflo(x1.x) + bflo(z1.x);  acc[9]  += bfhi(x1.x) + bfhi(z1.x);
            acc[10] += bflo(x1.y) + bflo(z1.y);  acc[11] += bfhi(x1.y) + bfhi(z1.y);
            acc[12] += bflo(x1.z) + bflo(z1.z);  acc[13] += bfhi(x1.z) + bfhi(z1.z);
            acc[14] += bflo(x1.w) + bflo(z1.w);  acc[15] += bfhi(x1.w) + bfhi(z1.w);
        }

        // epilogue: x = relu(dinv*(agg + h_self) + convb) + state ; write bf16 to LDS
        float dd = dinv[nodec];
        const unsigned short* hp = hb + (size_t)nodec * 64 + sub * 16;
        uint4 usl = *(const uint4*)hp;
        uint4 ush = *(const uint4*)(hp + 8);
        const unsigned short* sp = sb + (size_t)nodec * 64 + sub * 16;
        uint4 uvl = *(const uint4*)sp;
        uint4 uvh = *(const uint4*)(sp + 8);
        float4 c0 = *(const float4*)(convb + sub * 16);
        float4 c1 = *(const float4*)(convb + sub * 16 + 4);
        float4 c2 = *(const float4*)(convb + sub * 16 + 8);
        float4 c3 = *(const float4*)(convb + sub * 16 + 12);
        float sf[16] = {bflo(usl.x), bfhi(usl.x), bflo(usl.y), bfhi(usl.y),
                        bflo(usl.z), bfhi(usl.z), bflo(usl.w), bfhi(usl.w),
                        bflo(ush.x), bfhi(ush.x), bflo(ush.y), bfhi(ush.y),
                        bflo(ush.z), bfhi(ush.z), bflo(ush.w), bfhi(ush.w)};
        float sv[16] = {bflo(uvl.x), bfhi(uvl.x), bflo(uvl.y), bfhi(uvl.y),
                        bflo(uvl.z), bfhi(uvl.z), bflo(uvl.w), bfhi(uvl.w),
                        bflo(uvh.x), bfhi(uvh.x), bflo(uvh.y), bfhi(uvh.y),
                        bflo(uvh.z), bfhi(uvh.z), bflo(uvh.w), bfhi(uvh.w)};
        float cb[16] = {c0.x, c0.y, c0.z, c0.w, c1.x, c1.y, c1.z, c1.w,
                        c2.x, c2.y, c2.z, c2.w, c3.x, c3.y, c3.z, c3.w};
        float o[16];
        #pragma unroll
        for (int j = 0; j < 16; ++j) {
            float v = dd * (acc[j] + sf[j]) + cb[j];
            v = (v > 0.f) ? v : 0.f;
            o[j] = v + sv[j];
        }
        unsigned short* xp = xbL + (wid * 16 + g) * XB_STRIDE + sub * 16;
        uint4 pa = make_uint4(pack2bf(o[0], o[1]),  pack2bf(o[2], o[3]),
                              pack2bf(o[4], o[5]),  pack2bf(o[6], o[7]));
        uint4 pb = make_uint4(pack2bf(o[8], o[9]),  pack2bf(o[10], o[11]),
                              pack2bf(o[12], o[13]), pack2bf(o[14], o[15]));
        *(uint4*)xp       = pa;
        *(uint4*)(xp + 8) = pb;
    }
    __syncthreads();

    // ---- MLP phase (reads xbL / xgL from LDS) ----
    int quad = lane >> 4;
    int lm   = lane & 15;
    int node  = nbase + wid * 16 + lm;
    int nodec = (node < n) ? node : (n - 1);
    int rloc  = nodec / 6 - brow0;               // in [0,16)

    float bias1a = l1b[lm],      bias1b = l1b[16 + lm];
    float bias2a = l2b[lm],      bias2b = l2b[16 + lm];
    float w3a    = l3W[lm],      w3b    = l3W[16 + lm];
    float b3     = l3b[0];

    bf16x8 a0 = *(const bf16x8*)(xbL + (wid * 16 + lm) * XB_STRIDE + quad * 8);
    bf16x8 a1 = *(const bf16x8*)(xbL + (wid * 16 + lm) * XB_STRIDE + 32 + quad * 8);
    bf16x8 a2 = (bf16x8){0, 0, 0, 0, 0, 0, 0, 0};
    if (quad < 2) a2 = *(const bf16x8*)(xgL + rloc * 16 + quad * 8);

    f32x4v acc0 = (f32x4v){0.f, 0.f, 0.f, 0.f};
    f32x4v acc1 = acc0;
    {
        bf16x8 b;
        b = *(const bf16x8*)(w1p + (0 * 16 + lm) * 96 + 0 * 32 + quad * 8);
        acc0 = __builtin_amdgcn_mfma_f32_16x16x32_bf16(a0, b, acc0, 0, 0, 0);
        b = *(const bf16x8*)(w1p + (1 * 16 + lm) * 96 + 0 * 32 + quad * 8);
        acc1 = __builtin_amdgcn_mfma_f32_16x16x32_bf16(a0, b, acc1, 0, 0, 0);
        b = *(const bf16x8*)(w1p + (0 * 16 + lm) * 96 + 1 * 32 + quad * 8);
        acc0 = __builtin_amdgcn_mfma_f32_16x16x32_bf16(a1, b, acc0, 0, 0, 0);
        b = *(const bf16x8*)(w1p + (1 * 16 + lm) * 96 + 1 * 32 + quad * 8);
        acc1 = __builtin_amdgcn_mfma_f32_16x16x32_bf16(a1, b, acc1, 0, 0, 0);
        b = *(const bf16x8*)(w1p + (0 * 16 + lm) * 96 + 2 * 32 + quad * 8);
        acc0 = __builtin_amdgcn_mfma_f32_16x16x32_bf16(a2, b, acc0, 0, 0, 0);
        b = *(const bf16x8*)(w1p + (1 * 16 + lm) * 96 + 2 * 32 + quad * 8);
        acc1 = __builtin_amdgcn_mfma_f32_16x16x32_bf16(a2, b, acc1, 0, 0, 0);
    }

    unsigned short* myY = y1L[wid];
    #pragma unroll
    for (int r = 0; r < 4; ++r) {
        float v0 = acc0[r] + bias1a;
        float v1 = acc1[r] + bias1b;
        v0 = (v0 > 0.f) ? v0 : 0.01f * v0;
        v1 = (v1 > 0.f) ? v1 : 0.01f * v1;
        myY[(quad * 4 + r) * Y1_STRIDE + lm]      = f2bf(v0);
        myY[(quad * 4 + r) * Y1_STRIDE + 16 + lm] = f2bf(v1);
    }
    bf16x8 a2f = *(const bf16x8*)(myY + lm * Y1_STRIDE + quad * 8);
    f32x4v acc20 = (f32x4v){0.f, 0.f, 0.f, 0.f};
    f32x4v acc21 = acc20;
    {
        bf16x8 b;
        b = *(const bf16x8*)(w2p + (0 * 16 + lm) * 32 + quad * 8);
        acc20 = __builtin_amdgcn_mfma_f32_16x16x32_bf16(a2f, b, acc20, 0, 0, 0);
        b = *(const bf16x8*)(w2p + (1 * 16 + lm) * 32 + quad * 8);
        acc21 = __builtin_amdgcn_mfma_f32_16x16x32_bf16(a2f, b, acc21, 0, 0, 0);
    }

    float part[4];
    #pragma unroll
    for (int r = 0; r < 4; ++r) {
        float y2a = acc20[r] + bias2a;
        float y2b = acc21[r] + bias2b;
        y2a = (y2a > 0.f) ? y2a : 0.01f * y2a;
        y2b = (y2b > 0.f) ? y2b : 0.01f * y2b;
        part[r] = y2a * w3a + y2b * w3b;
    }
    #pragma unroll
    for (int st = 1; st < 16; st <<= 1) {
        #pragma unroll
        for (int r = 0; r < 4; ++r) part[r] += __shfl_xor(part[r], st, 64);
    }
    if (lm == 0) {
        #pragma unroll
        for (int r = 0; r < 4; ++r) {
            float a3 = part[r] + b3;
            conc[wid * 16 + quad * 4 + r] = (a3 > 20.f) ? a3 : log1pf(expf(a3));
        }
    }
    __syncthreads();

    float myabs = 0.f;
    if (tid < 96) {
        int gnode = nbase + tid;
        if (gnode < n) {
            int g0 = (tid / 6) * 6;
            float s = 0.f;
            #pragma unroll
            for (int i = 0; i < 6; ++i) s += conc[g0 + i];
            float c = conc[tid];
            out[gnode] = c / (s + 1e-20f);
            myabs = fabsf(c);
        }
    }
    #pragma unroll
    for (int off = 32; off > 0; off >>= 1) myabs += __shfl_down(myabs, off, 64);
    if (lane == 0) wsum[wid] = myabs;
    __syncthreads();
    if (tid == 0) {
        float total = wsum[0] + wsum[1] + wsum[2] + wsum[3] + wsum[4] + wsum[5];
        atomicAdd(regptr, total * (1.0f / (float)N_NODES));
    }
}

extern "C" void kernel_launch(void* const* d_in, const int* in_sizes, int n_in,
                              void* d_out, int out_size, void* d_ws, size_t ws_size,
                              hipStream_t stream) {
    const float* state = (const float*)d_in[0];
    const int*   ei    = (const int*)d_in[1];
    const float* convW = (const float*)d_in[2];
    const float* convb = (const float*)d_in[3];
    const float* gW1   = (const float*)d_in[4];
    const float* gb1   = (const float*)d_in[5];
    const float* gW2   = (const float*)d_in[6];
    const float* gb2   = (const float*)d_in[7];
    const float* l1W   = (const float*)d_in[8];
    const float* l1b   = (const float*)d_in[9];
    const float* l2W   = (const float*)d_in[10];
    const float* l2b   = (const float*)d_in[11];
    const float* l3W   = (const float*)d_in[12];
    const float* l3b   = (const float*)d_in[13];

    const int n = N_NODES, E = N_EDGES, B = B_ROWS;
    const int* src = ei;
    const int* dst = ei + E;

    // ---- workspace layout ----
    char* w = (char*)d_ws;
    unsigned int* flags  = (unsigned int*)w; w += NBIN * 4;      // lookback flags
    unsigned int* ticket = (unsigned int*)w; w += 16 * 4;        // + ticket (memset together)
    int*  hist    = (int*)w;                 w += (size_t)NBIN * NCHUNK * 4;  // 1.37 MB
    int*  binStart= (int*)w;                 w += (NBIN + 16) * 4;
    int2* bb      = (int2*)w;                w += (size_t)E * 8;  // 9.6 MB bucketed pairs
    int*  rowptr  = (int*)w;                 w += (NPAD + 16) * 4;
    float* dinv   = (float*)w;               w += NPAD * 4;
    int*   csr    = (int*)w;                 w += (size_t)E * 4;
    float* hregion= (float*)w;               w += (size_t)n * 64 * 4; // 38.4 MB
    unsigned short* y1b = (unsigned short*)w; w += (size_t)B_ROWS * 256 * 2; // 12.8 MB
    unsigned short* w1b = (unsigned short*)w; w += 98304 * 2;
    unsigned short* w1p = (unsigned short*)w; w += 3072 * 2;
    unsigned short* w2p = (unsigned short*)w; w += 1024 * 2;
    unsigned short* wcb = (unsigned short*)w; w += 4096 * 2;
    unsigned short* w2b = (unsigned short*)w; w += 4096 * 2;
    // hregion: hb = [0..19.2MB) bf16 h*dinv (k2) ; sb = [19.2..38.4MB) bf16 state (k1)
    unsigned short* hb  = (unsigned short*)hregion;
    unsigned short* sb  = (unsigned short*)(hregion + 4800000);

    float* out    = (float*)d_out;
    float* regptr = out + n;

    // one tiny memset: lookback flags + ticket (contiguous at workspace start)
    hipMemsetAsync(flags, 0, (NBIN + 16) * 4, stream);

    k1_hist_cast_prep<<<HIST_BLOCKS + CAST_BLOCKS + PREP_BLOCKS, 512, 0, stream>>>(
        dst, hist, state, sb, convW, gW1, gW2, l1W, l2W, wcb, w1b, w1p, w2p, w2b, E);
    sort_scan<<<NBIN, 512, 0, stream>>>(hist, binStart, flags, ticket, regptr);
    sort_scatter<<<NCHUNK, 512, 0, stream>>>(src, dst, hist, bb, E);
    sort_finalize<<<NBIN, 512, 0, stream>>>(bb, binStart, csr, rowptr, dinv, n);
    k2_gemm1_conv<<<GEMM1_BLOCKS + CONV_BLOCKS2, 512, 0, stream>>>(
        sb, wcb, dinv, hb, w1b, gb1, y1b, n, B);
    k3_fused<<<FUSED_BLOCKS, 384, 0, stream>>>(
        rowptr, csr, hb, sb, dinv, convb, y1b, w2b, gb2, w1p, w2p,
        l1b, l2b, l3W, l3b, out, regptr, n, E, B);
}

// Round 9
// 255.000 us; speedup vs baseline: 1.1134x; 1.1134x over previous
//
#include <hip/hip_runtime.h>
#include <math.h>

#define N_NODES 150000
#define N_EDGES 1200000
#define C 64
#define ACT 6
#define B_ROWS 25000   // N/ACT
#define GLOB 256
#define GOUT 10
#define H 32

#define NPAD 150016            // N rounded up (alignment)
#define SCAN_CHUNK 1024
#define NSCAN 147              // ceil(150000/1024)

// k1 = degree+rank (returning atomics) || state->bf16 cast || weight prep (256-thread blocks)
#define DEGREE_BLOCKS 4688     // ceil(1.2M/256), 1 edge/thread
#define CAST_BLOCKS 4688       // ceil(9.6M elems / (256*8))
#define PREP_BLOCKS 432        // 110592/256

// k2 = gemm1 (XCD-quartet swizzled, 16 inert pads) || conv || fill, 512 threads
#define GEMM1_BLOCKS 800       // 25 slots * 32 (196 real mb + 4 pad)
#define CONV_BLOCKS2 1172      // ceil(9375 row-tiles / 8 waves)
#define FILL_BLOCKS2 2344      // ceil(1.2M/512)

// k3 = fused gather+gemm2+mlp: 96 nodes/block, 384 threads
#define FUSED_BLOCKS 1563      // ceil(150000/96)

typedef short bf16x8 __attribute__((ext_vector_type(8)));
typedef float f32x4v __attribute__((ext_vector_type(4)));

// ---- bf16 helpers ----
__device__ __forceinline__ unsigned short f2bf(float f) {
    unsigned int u = __builtin_bit_cast(unsigned int, f);
    unsigned int r = (u + 0x7fffu + ((u >> 16) & 1u)) >> 16;   // RTNE
    return (unsigned short)r;
}
__device__ __forceinline__ unsigned int pack2bf(float a, float b) {
    return (unsigned int)f2bf(a) | ((unsigned int)f2bf(b) << 16);
}
__device__ __forceinline__ float bflo(unsigned int u) {
    return __builtin_bit_cast(float, u << 16);
}
__device__ __forceinline__ float bfhi(unsigned int u) {
    return __builtin_bit_cast(float, u & 0xffff0000u);
}

// ======== k1: degree+rank || state->bf16 cast || weight prep ========
__global__ __launch_bounds__(256) void k1_degree_cast_prep(
        const int* __restrict__ dst, int* __restrict__ counts, int* __restrict__ rank,
        const float* __restrict__ state, unsigned short* __restrict__ sb,
        const float* __restrict__ convW, const float* __restrict__ gW1,
        const float* __restrict__ gW2,
        const float* __restrict__ l1W, const float* __restrict__ l2W,
        unsigned short* __restrict__ wcb, unsigned short* __restrict__ w1b,
        unsigned short* __restrict__ w1p, unsigned short* __restrict__ w2p,
        unsigned short* __restrict__ w2b, int E) {
    int bi = blockIdx.x;
    if (bi < DEGREE_BLOCKS) {
        int e = bi * 256 + threadIdx.x;
        if (e < E) rank[e] = atomicAdd(&counts[dst[e]], 1);
        return;
    }
    bi -= DEGREE_BLOCKS;
    if (bi < CAST_BLOCKS) {
        int idx = (bi * 256 + threadIdx.x) * 8;
        if (idx < N_NODES * C) {
            float4 a = *(const float4*)(state + idx);
            float4 b = *(const float4*)(state + idx + 4);
            uint4 o = make_uint4(pack2bf(a.x, a.y), pack2bf(a.z, a.w),
                                 pack2bf(b.x, b.y), pack2bf(b.z, b.w));
            *(uint4*)(sb + idx) = o;
        }
        return;
    }
    bi -= CAST_BLOCKS;
    int j = bi * 256 + threadIdx.x;
    if (j < 4096) {
        wcb[j] = f2bf(convW[j]);
    } else if (j < 102400) {
        int k = j - 4096;
        w1b[k] = f2bf(gW1[k]);
    } else if (j < 105472) {
        int k = j - 102400;
        int r = k / 96, c = k - r * 96;
        w1p[k] = (c < 74) ? f2bf(l1W[r * 74 + c]) : 0;
    } else if (j < 106496) {
        int k = j - 105472;
        w2p[k] = f2bf(l2W[k]);
    } else {
        int k = j - 106496;          // j < 110592 exactly (432 blocks)
        int r = k >> 8, c = k & 255;
        w2b[k] = (r < 10) ? f2bf(gW2[r * 256 + c]) : 0;
    }
}

// ---------------- prefix scan (2 kernels) ----------------
__global__ void scan_block(const int* __restrict__ counts, int* __restrict__ rowptr,
                           int* __restrict__ bsum, int n) {
    __shared__ int lds[256];
    int base = blockIdx.x * SCAN_CHUNK;
    int t = threadIdx.x;
    int v[4]; int s = 0;
    #pragma unroll
    for (int i = 0; i < 4; ++i) {
        int idx = base + t * 4 + i;
        v[i] = (idx < n) ? counts[idx] : 0;
        s += v[i];
    }
    lds[t] = s; __syncthreads();
    for (int off = 1; off < 256; off <<= 1) {
        int x = (t >= off) ? lds[t - off] : 0;
        __syncthreads();
        lds[t] += x;
        __syncthreads();
    }
    int excl = lds[t] - s;
    if (t == 255) bsum[blockIdx.x] = lds[255];
    int run = excl;
    #pragma unroll
    for (int i = 0; i < 4; ++i) {
        int idx = base + t * 4 + i;
        if (idx < n) rowptr[idx] = run;
        run += v[i];
    }
}

// scan_add: each 256-block computes its own bsum prefix (<=147 entries, 64-lane reduce)
__global__ __launch_bounds__(256) void scan_add(
        int* __restrict__ rowptr, const int* __restrict__ bsum,
        const int* __restrict__ counts, float* __restrict__ dinv,
        float* __restrict__ regptr, int n, int E) {
    __shared__ int sofs;
    int b = blockIdx.x;
    int t = threadIdx.x;
    int chunk = b >> 2;                        // 256-thread block lies in one 1024-chunk
    if (t < 64) {
        int s = 0;
        for (int j = t; j < chunk; j += 64) s += bsum[j];
        #pragma unroll
        for (int off = 32; off > 0; off >>= 1) s += __shfl_down(s, off, 64);
        if (t == 0) sofs = s;
    }
    __syncthreads();
    int i = b * 256 + t;
    if (i == 0) *regptr = 0.f;
    if (i < n) {
        rowptr[i] += sofs;
        dinv[i] = rsqrtf((float)counts[i] + 1.0f);
    }
    if (i == n) rowptr[n] = E;
}

// ======== k2: gemm1 (MFMA, XCD-quartet swizzle, 25.6KB LDS) || conv (MFMA) || CSR fill =======
#define BS2 200   // shorts per LDS row: 192 cols + 8 pad
__global__ __launch_bounds__(512, 8) void k2_gemm1_conv_fill(
        const unsigned short* __restrict__ sb,    // bf16(state): [150000][64] == [25000][384]
        const unsigned short* __restrict__ wcb,
        const float* __restrict__ dinv,
        unsigned short* __restrict__ hb,
        const int* __restrict__ src, const int* __restrict__ dst,
        const int* __restrict__ rowptr, const int* __restrict__ rank,
        int* __restrict__ csr,
        const unsigned short* __restrict__ Wb,    // w1b [256][384] bf16
        const float* __restrict__ bias,           // gb1
        unsigned short* __restrict__ y1b,         // [25000][256] bf16 out
        int n, int E, int M) {
    __shared__ unsigned short Blds[64 * BS2];     // 25600 B -> 4 blocks/CU (wave cap)

    int bi  = blockIdx.x;
    int tid = threadIdx.x;

    if (bi < GEMM1_BLOCKS) {
        // ---- XCD-quartet swizzle: 4 col-quarter blocks of one mb land on the SAME XCD
        //      (XCD = blockIdx % 8 round-robin) so the shared 96KB A-panel hits local L2.
        int slot = bi >> 5;                       // 0..24
        int q    = (bi >> 3) & 3;                 // col-quarter
        int xcd  = bi & 7;
        int mb   = slot * 8 + xcd;                // 0..199; 196..199 inert
        if (mb >= 196) return;
        int col0 = q * 64;

        int wave = tid >> 6;
        int lane = tid & 63;
        int quad = lane >> 4;
        int lm   = lane & 15;
        int row0 = mb * 128 + wave * 16;
        int arow = row0 + lm;
        if (arow >= M) arow = M - 1;
        const unsigned short* ap = sb + (size_t)arow * 384 + quad * 8;

        f32x4v acc[4];
        #pragma unroll
        for (int t = 0; t < 4; ++t) acc[t] = (f32x4v){0.f, 0.f, 0.f, 0.f};

        // ---- stage 0: K cols [0,192) ----
        #pragma unroll
        for (int i = 0; i < 3; ++i) {
            int seg = i * 512 + tid;
            int row = seg / 24;                  // 24 uint4 per row
            int off = (seg - row * 24) * 8;
            *(uint4*)(&Blds[row * BS2 + off]) = *(const uint4*)(Wb + (size_t)(col0 + row) * 384 + off);
        }
        {
            bf16x8 af[6];
            #pragma unroll
            for (int ks = 0; ks < 6; ++ks) af[ks] = *(const bf16x8*)(ap + ks * 32);
            __syncthreads();
            #pragma unroll
            for (int ks = 0; ks < 6; ++ks) {
                #pragma unroll
                for (int t = 0; t < 4; ++t) {
                    bf16x8 bfr = *(const bf16x8*)(&Blds[(t * 16 + lm) * BS2 + ks * 32 + quad * 8]);
                    acc[t] = __builtin_amdgcn_mfma_f32_16x16x32_bf16(af[ks], bfr, acc[t], 0, 0, 0);
                }
            }
        }
        __syncthreads();
        // ---- stage 1: K cols [192,384) ----
        #pragma unroll
        for (int i = 0; i < 3; ++i) {
            int seg = i * 512 + tid;
            int row = seg / 24;
            int off = (seg - row * 24) * 8;
            *(uint4*)(&Blds[row * BS2 + off]) = *(const uint4*)(Wb + (size_t)(col0 + row) * 384 + 192 + off);
        }
        {
            bf16x8 af[6];
            #pragma unroll
            for (int ks = 0; ks < 6; ++ks) af[ks] = *(const bf16x8*)(ap + 192 + ks * 32);
            __syncthreads();
            #pragma unroll
            for (int ks = 0; ks < 6; ++ks) {
                #pragma unroll
                for (int t = 0; t < 4; ++t) {
                    bf16x8 bfr = *(const bf16x8*)(&Blds[(t * 16 + lm) * BS2 + ks * 32 + quad * 8]);
                    acc[t] = __builtin_amdgcn_mfma_f32_16x16x32_bf16(af[ks], bfr, acc[t], 0, 0, 0);
                }
            }
        }

        #pragma unroll
        for (int t = 0; t < 4; ++t) {
            int nn = col0 + t * 16 + lm;
            float bv = bias[nn];
            #pragma unroll
            for (int r = 0; r < 4; ++r) {
                int m = row0 + quad * 4 + r;
                if (m < M) {
                    float v = acc[t][r] + bv;
                    v = (v > 0.f) ? v : 0.01f * v;
                    y1b[(size_t)m * 256 + nn] = f2bf(v);
                }
            }
        }
        return;
    }

    if (bi < GEMM1_BLOCKS + CONV_BLOCKS2) {
        // ---- conv: h = bf16(sb @ convW^T) * dinv ----
        int cb   = bi - GEMM1_BLOCKS;
        int wid  = tid >> 6;
        int lane = tid & 63;
        int quad = lane >> 4;
        int lm   = lane & 15;
        int row0 = (cb * 8 + wid) * 16;
        if (row0 >= n) return;                    // n = 150000 = 16*9375

        const unsigned short* ap = sb + (size_t)(row0 + lm) * 64 + quad * 8;
        bf16x8 a0 = *(const bf16x8*)ap;
        bf16x8 a1 = *(const bf16x8*)(ap + 32);

        f32x4v acc[4];
        #pragma unroll
        for (int t = 0; t < 4; ++t) acc[t] = (f32x4v){0.f, 0.f, 0.f, 0.f};
        #pragma unroll
        for (int t = 0; t < 4; ++t) {
            const unsigned short* bp = wcb + (size_t)(t * 16 + lm) * 64 + quad * 8;
            bf16x8 b0 = *(const bf16x8*)bp;
            bf16x8 b1 = *(const bf16x8*)(bp + 32);
            acc[t] = __builtin_amdgcn_mfma_f32_16x16x32_bf16(a0, b0, acc[t], 0, 0, 0);
            acc[t] = __builtin_amdgcn_mfma_f32_16x16x32_bf16(a1, b1, acc[t], 0, 0, 0);
        }

        float dv[4];
        #pragma unroll
        for (int r = 0; r < 4; ++r) dv[r] = dinv[row0 + quad * 4 + r];
        #pragma unroll
        for (int t = 0; t < 4; ++t) {
            #pragma unroll
            for (int r = 0; r < 4; ++r) {
                int m = row0 + quad * 4 + r;
                hb[(size_t)m * 64 + t * 16 + lm] = f2bf(acc[t][r] * dv[r]);
            }
        }
        return;
    }

    // ---- fill: CSR scatter (rank precomputed in k1; plain store) ----
    int e = (bi - GEMM1_BLOCKS - CONV_BLOCKS2) * 512 + tid;
    if (e < E) {
        int d = dst[e];
        csr[rowptr[d] + rank[e]] = src[e];
    }
}

// ======== k3: fused gather (4 lanes/node, 2-deep, LDS x) + inline gemm2 + MLP ========
#define XB_STRIDE 72    // shorts; 144B rows -> 16B-aligned uint4, 2-way-free bank stride
#define Y1_STRIDE 40
__global__ __launch_bounds__(384, 6) void k3_fused(
        const int* __restrict__ rowptr, const int* __restrict__ csr,
        const unsigned short* __restrict__ hb, const unsigned short* __restrict__ sb,
        const float* __restrict__ dinv, const float* __restrict__ convb,
        const unsigned short* __restrict__ y1b,   // [25000][256] bf16
        const unsigned short* __restrict__ w2b,   // [16][256] bf16 zero-padded
        const float* __restrict__ b2,             // gb2 [10]
        const unsigned short* __restrict__ w1p,   // [32][96] bf16 zero-padded
        const unsigned short* __restrict__ w2p,   // [32][32] bf16
        const float* __restrict__ l1b, const float* __restrict__ l2b,
        const float* __restrict__ l3W, const float* __restrict__ l3b,
        float* __restrict__ out, float* __restrict__ regptr,
        int n, int E, int M) {
    __shared__ unsigned short xbL[96 * XB_STRIDE];   // 13824 B: x = relu(conv)+state, bf16
    __shared__ unsigned short xgL[16 * 16];          // 512 B: this block's 16 gemm2 rows
    __shared__ unsigned short y1L[6][16 * Y1_STRIDE];
    __shared__ float conc[96];
    __shared__ float wsum[6];

    int tid  = threadIdx.x;
    int wid  = tid >> 6;
    int lane = tid & 63;
    int nbase = blockIdx.x * 96;
    int brow0 = nbase / 6;                     // 16 B-rows per block

    // ---- inline gemm2 on wave 0: xg[brow0..brow0+16) = leaky(y1 @ W2^T + b2) ----
    if (wid == 0) {
        int quad = lane >> 4;
        int lm   = lane & 15;
        int arow = brow0 + lm;
        if (arow >= M) arow = M - 1;
        const unsigned short* ap = y1b + (size_t)arow * 256 + quad * 8;
        const unsigned short* bp = w2b + (size_t)lm * 256 + quad * 8;
        f32x4v acc2 = (f32x4v){0.f, 0.f, 0.f, 0.f};
        #pragma unroll
        for (int ks = 0; ks < 8; ++ks) {
            bf16x8 a = *(const bf16x8*)(ap + ks * 32);
            bf16x8 b = *(const bf16x8*)(bp + ks * 32);
            acc2 = __builtin_amdgcn_mfma_f32_16x16x32_bf16(a, b, acc2, 0, 0, 0);
        }
        float bv = (lane & 15) < 10 ? b2[lane & 15] : 0.f;
        #pragma unroll
        for (int r = 0; r < 4; ++r) {
            float v = acc2[r] + bv;
            v = (v > 0.f) ? v : 0.01f * v;     // rows >=10: W=0,b=0 -> exact 0
            xgL[(quad * 4 + r) * 16 + lm] = f2bf(v);
        }
    }

    // ---- gather: 6 waves x 16 nodes, 4 lanes/node (16 channels/lane), 2 neighbors/iter ----
    {
        int g   = lane >> 2;
        int sub = lane & 3;
        int node = nbase + wid * 16 + g;
        bool valid = node < n;
        int nodec = valid ? node : (n - 1);
        int beg = rowptr[nodec], end = rowptr[nodec + 1];
        int deg = valid ? (end - beg) : 0;

        float acc[16];
        #pragma unroll
        for (int j = 0; j < 16; ++j) acc[j] = 0.f;

        int eid = 0;
        for (int i = 0; i < deg; i += 2) {
            if ((i & 3) == 0) {
                int q2 = beg + i + sub; if (q2 > E - 1) q2 = E - 1;
                eid = csr[q2];
            }
            int rem = deg - i;                        // >= 1, group-uniform
            int b0  = (g << 2) + (i & 2);
            int s0 = __shfl(eid, b0, 64);
            int s1 = __shfl(eid, b0 + 1, 64);
            const unsigned short* h0 = hb + (size_t)s0 * 64 + sub * 16;
            uint4 x0 = *(const uint4*)h0;
            uint4 x1 = *(const uint4*)(h0 + 8);
            uint4 z0 = make_uint4(0u, 0u, 0u, 0u), z1 = z0;
            if (rem > 1) {
                const unsigned short* h1 = hb + (size_t)s1 * 64 + sub * 16;
                z0 = *(const uint4*)h1;
                z1 = *(const uint4*)(h1 + 8);
            }
            acc[0]  += bflo(x0.x) + bflo(z0.x);  acc[1]  += bfhi(x0.x) + bfhi(z0.x);
            acc[2]  += bflo(x0.y) + bflo(z0.y);  acc[3]  += bfhi(x0.y) + bfhi(z0.y);
            acc[4]  += bflo(x0.z) + bflo(z0.z);  acc[5]  += bfhi(x0.z) + bfhi(z0.z);
            acc[6]  += bflo(x0.w) + bflo(z0.w);  acc[7]  += bfhi(x0.w) + bfhi(z0.w);
            acc[8]  += bflo(x1.x) + bflo(z1.x);  acc[9]  += bfhi(x1.x) + bfhi(z1.x);
            acc[10] += bflo(x1.y) + bflo(z1.y);  acc[11] += bfhi(x1.y) + bfhi(z1.y);
            acc[12] += bflo(x1.z) + bflo(z1.z);  acc[13] += bfhi(x1.z) + bfhi(z1.z);
            acc[14] += bflo(x1.w) + bflo(z1.w);  acc[15] += bfhi(x1.w) + bfhi(z1.w);
        }

        // epilogue: x = relu(dinv*(agg + h_self) + convb) + state ; write bf16 to LDS
        float dd = dinv[nodec];
        const unsigned short* hp = hb + (size_t)nodec * 64 + sub * 16;
        uint4 usl = *(const uint4*)hp;
        uint4 ush = *(const uint4*)(hp + 8);
        const unsigned short* sp = sb + (size_t)nodec * 64 + sub * 16;
        uint4 uvl = *(const uint4*)sp;
        uint4 uvh = *(const uint4*)(sp + 8);
        float4 c0 = *(const float4*)(convb + sub * 16);
        float4 c1 = *(const float4*)(convb + sub * 16 + 4);
        float4 c2 = *(const float4*)(convb + sub * 16 + 8);
        float4 c3 = *(const float4*)(convb + sub * 16 + 12);
        float sf[16] = {bflo(usl.x), bfhi(usl.x), bflo(usl.y), bfhi(usl.y),
                        bflo(usl.z), bfhi(usl.z), bflo(usl.w), bfhi(usl.w),
                        bflo(ush.x), bfhi(ush.x), bflo(ush.y), bfhi(ush.y),
                        bflo(ush.z), bfhi(ush.z), bflo(ush.w), bfhi(ush.w)};
        float sv[16] = {bflo(uvl.x), bfhi(uvl.x), bflo(uvl.y), bfhi(uvl.y),
                        bflo(uvl.z), bfhi(uvl.z), bflo(uvl.w), bfhi(uvl.w),
                        bflo(uvh.x), bfhi(uvh.x), bflo(uvh.y), bfhi(uvh.y),
                        bflo(uvh.z), bfhi(uvh.z), bflo(uvh.w), bfhi(uvh.w)};
        float cb[16] = {c0.x, c0.y, c0.z, c0.w, c1.x, c1.y, c1.z, c1.w,
                        c2.x, c2.y, c2.z, c2.w, c3.x, c3.y, c3.z, c3.w};
        float o[16];
        #pragma unroll
        for (int j = 0; j < 16; ++j) {
            float v = dd * (acc[j] + sf[j]) + cb[j];
            v = (v > 0.f) ? v : 0.f;
            o[j] = v + sv[j];
        }
        unsigned short* xp = xbL + (wid * 16 + g) * XB_STRIDE + sub * 16;
        uint4 pa = make_uint4(pack2bf(o[0], o[1]),  pack2bf(o[2], o[3]),
                              pack2bf(o[4], o[5]),  pack2bf(o[6], o[7]));
        uint4 pb = make_uint4(pack2bf(o[8], o[9]),  pack2bf(o[10], o[11]),
                              pack2bf(o[12], o[13]), pack2bf(o[14], o[15]));
        *(uint4*)xp       = pa;
        *(uint4*)(xp + 8) = pb;
    }
    __syncthreads();

    // ---- MLP phase (reads xbL / xgL from LDS) ----
    int quad = lane >> 4;
    int lm   = lane & 15;
    int node  = nbase + wid * 16 + lm;
    int nodec = (node < n) ? node : (n - 1);
    int rloc  = nodec / 6 - brow0;               // in [0,16)

    float bias1a = l1b[lm],      bias1b = l1b[16 + lm];
    float bias2a = l2b[lm],      bias2b = l2b[16 + lm];
    float w3a    = l3W[lm],      w3b    = l3W[16 + lm];
    float b3     = l3b[0];

    bf16x8 a0 = *(const bf16x8*)(xbL + (wid * 16 + lm) * XB_STRIDE + quad * 8);
    bf16x8 a1 = *(const bf16x8*)(xbL + (wid * 16 + lm) * XB_STRIDE + 32 + quad * 8);
    bf16x8 a2 = (bf16x8){0, 0, 0, 0, 0, 0, 0, 0};
    if (quad < 2) a2 = *(const bf16x8*)(xgL + rloc * 16 + quad * 8);

    f32x4v acc0 = (f32x4v){0.f, 0.f, 0.f, 0.f};
    f32x4v acc1 = acc0;
    {
        bf16x8 b;
        b = *(const bf16x8*)(w1p + (0 * 16 + lm) * 96 + 0 * 32 + quad * 8);
        acc0 = __builtin_amdgcn_mfma_f32_16x16x32_bf16(a0, b, acc0, 0, 0, 0);
        b = *(const bf16x8*)(w1p + (1 * 16 + lm) * 96 + 0 * 32 + quad * 8);
        acc1 = __builtin_amdgcn_mfma_f32_16x16x32_bf16(a0, b, acc1, 0, 0, 0);
        b = *(const bf16x8*)(w1p + (0 * 16 + lm) * 96 + 1 * 32 + quad * 8);
        acc0 = __builtin_amdgcn_mfma_f32_16x16x32_bf16(a1, b, acc0, 0, 0, 0);
        b = *(const bf16x8*)(w1p + (1 * 16 + lm) * 96 + 1 * 32 + quad * 8);
        acc1 = __builtin_amdgcn_mfma_f32_16x16x32_bf16(a1, b, acc1, 0, 0, 0);
        b = *(const bf16x8*)(w1p + (0 * 16 + lm) * 96 + 2 * 32 + quad * 8);
        acc0 = __builtin_amdgcn_mfma_f32_16x16x32_bf16(a2, b, acc0, 0, 0, 0);
        b = *(const bf16x8*)(w1p + (1 * 16 + lm) * 96 + 2 * 32 + quad * 8);
        acc1 = __builtin_amdgcn_mfma_f32_16x16x32_bf16(a2, b, acc1, 0, 0, 0);
    }

    unsigned short* myY = y1L[wid];
    #pragma unroll
    for (int r = 0; r < 4; ++r) {
        float v0 = acc0[r] + bias1a;
        float v1 = acc1[r] + bias1b;
        v0 = (v0 > 0.f) ? v0 : 0.01f * v0;
        v1 = (v1 > 0.f) ? v1 : 0.01f * v1;
        myY[(quad * 4 + r) * Y1_STRIDE + lm]      = f2bf(v0);
        myY[(quad * 4 + r) * Y1_STRIDE + 16 + lm] = f2bf(v1);
    }
    bf16x8 a2f = *(const bf16x8*)(myY + lm * Y1_STRIDE + quad * 8);
    f32x4v acc20 = (f32x4v){0.f, 0.f, 0.f, 0.f};
    f32x4v acc21 = acc20;
    {
        bf16x8 b;
        b = *(const bf16x8*)(w2p + (0 * 16 + lm) * 32 + quad * 8);
        acc20 = __builtin_amdgcn_mfma_f32_16x16x32_bf16(a2f, b, acc20, 0, 0, 0);
        b = *(const bf16x8*)(w2p + (1 * 16 + lm) * 32 + quad * 8);
        acc21 = __builtin_amdgcn_mfma_f32_16x16x32_bf16(a2f, b, acc21, 0, 0, 0);
    }

    float part[4];
    #pragma unroll
    for (int r = 0; r < 4; ++r) {
        float y2a = acc20[r] + bias2a;
        float y2b = acc21[r] + bias2b;
        y2a = (y2a > 0.f) ? y2a : 0.01f * y2a;
        y2b = (y2b > 0.f) ? y2b : 0.01f * y2b;
        part[r] = y2a * w3a + y2b * w3b;
    }
    #pragma unroll
    for (int st = 1; st < 16; st <<= 1) {
        #pragma unroll
        for (int r = 0; r < 4; ++r) part[r] += __shfl_xor(part[r], st, 64);
    }
    if (lm == 0) {
        #pragma unroll
        for (int r = 0; r < 4; ++r) {
            float a3 = part[r] + b3;
            conc[wid * 16 + quad * 4 + r] = (a3 > 20.f) ? a3 : log1pf(expf(a3));
        }
    }
    __syncthreads();

    float myabs = 0.f;
    if (tid < 96) {
        int gnode = nbase + tid;
        if (gnode < n) {
            int g0 = (tid / 6) * 6;
            float s = 0.f;
            #pragma unroll
            for (int i = 0; i < 6; ++i) s += conc[g0 + i];
            float c = conc[tid];
            out[gnode] = c / (s + 1e-20f);
            myabs = fabsf(c);
        }
    }
    #pragma unroll
    for (int off = 32; off > 0; off >>= 1) myabs += __shfl_down(myabs, off, 64);
    if (lane == 0) wsum[wid] = myabs;
    __syncthreads();
    if (tid == 0) {
        float total = wsum[0] + wsum[1] + wsum[2] + wsum[3] + wsum[4] + wsum[5];
        atomicAdd(regptr, total * (1.0f / (float)N_NODES));
    }
}

extern "C" void kernel_launch(void* const* d_in, const int* in_sizes, int n_in,
                              void* d_out, int out_size, void* d_ws, size_t ws_size,
                              hipStream_t stream) {
    const float* state = (const float*)d_in[0];
    const int*   ei    = (const int*)d_in[1];
    const float* convW = (const float*)d_in[2];
    const float* convb = (const float*)d_in[3];
    const float* gW1   = (const float*)d_in[4];
    const float* gb1   = (const float*)d_in[5];
    const float* gW2   = (const float*)d_in[6];
    const float* gb2   = (const float*)d_in[7];
    const float* l1W   = (const float*)d_in[8];
    const float* l1b   = (const float*)d_in[9];
    const float* l2W   = (const float*)d_in[10];
    const float* l2b   = (const float*)d_in[11];
    const float* l3W   = (const float*)d_in[12];
    const float* l3b   = (const float*)d_in[13];

    const int n = N_NODES, E = N_EDGES, B = B_ROWS;
    const int* src = ei;
    const int* dst = ei + E;

    // ---- workspace layout ----
    char* w = (char*)d_ws;
    int*   counts = (int*)w;                 w += NPAD * 4;
    int*   rank   = (int*)w;                 w += (size_t)E * 4;
    int*   rowptr = (int*)w;                 w += NPAD * 4;
    int*   bsum   = (int*)w;                 w += 256 * 4;
    float* dinv   = (float*)w;               w += NPAD * 4;
    int*   csr    = (int*)w;                 w += (size_t)E * 4;
    float* hregion= (float*)w;               w += (size_t)n * 64 * 4; // 38.4 MB
    unsigned short* y1b = (unsigned short*)w; w += (size_t)B_ROWS * 256 * 2; // 12.8 MB
    unsigned short* w1b = (unsigned short*)w; w += 98304 * 2;
    unsigned short* w1p = (unsigned short*)w; w += 3072 * 2;
    unsigned short* w2p = (unsigned short*)w; w += 1024 * 2;
    unsigned short* wcb = (unsigned short*)w; w += 4096 * 2;
    unsigned short* w2b = (unsigned short*)w; w += 4096 * 2;
    // hregion: hb = [0..19.2MB) bf16 h*dinv (k2) ; sb = [19.2..38.4MB) bf16 state (k1)
    unsigned short* hb  = (unsigned short*)hregion;
    unsigned short* sb  = (unsigned short*)(hregion + 4800000);

    float* out    = (float*)d_out;
    float* regptr = out + n;

    hipMemsetAsync(counts, 0, NPAD * 4, stream);

    k1_degree_cast_prep<<<DEGREE_BLOCKS + CAST_BLOCKS + PREP_BLOCKS, 256, 0, stream>>>(
        dst, counts, rank, state, sb, convW, gW1, gW2, l1W, l2W, wcb, w1b, w1p, w2p, w2b, E);
    scan_block<<<NSCAN, 256, 0, stream>>>(counts, rowptr, bsum, n);
    scan_add<<<(n + 256) / 256, 256, 0, stream>>>(rowptr, bsum, counts, dinv, regptr, n, E);
    k2_gemm1_conv_fill<<<GEMM1_BLOCKS + CONV_BLOCKS2 + FILL_BLOCKS2, 512, 0, stream>>>(
        sb, wcb, dinv, hb, src, dst, rowptr, rank, csr, w1b, gb1, y1b, n, E, B);
    k3_fused<<<FUSED_BLOCKS, 384, 0, stream>>>(
        rowptr, csr, hb, sb, dinv, convb, y1b, w2b, gb2, w1p, w2p,
        l1b, l2b, l3W, l3b, out, regptr, n, E, B);
}